// Round 7
// baseline (943.974 us; speedup 1.0000x reference)
//
#include <hip/hip_runtime.h>
#include <hip/hip_bf16.h>
#include <math.h>

#define H 64
#define FIN 19
#define EPSLN 1e-5f
#define NBLK 256
#define NTHR 256
#define NBARS 12

// f32 weight workspace layout (element offsets), all natural row-major.
#define OFF_PW   0        // 19*64
#define OFF_PB   1216     // 64
#define OFF_EW   1280     // 2*4096
#define OFF_EB   9472     // 128
#define OFF_G    9600     // 128
#define OFF_BT   9728     // 128
#define OFF_W1   9856     // 3*4096
#define OFF_W2   22144    // 3*4096
#define OFF_B1   34432    // 192
#define OFF_B2   34624    // 192
#define OFF_HW1  34816    // 4096 (natural)
#define OFF_HB1  38912    // 64
#define OFF_HW2  38976    // 64
#define OFF_HB2  39040    // 1
#define WTS_TOTAL 39041

__device__ __forceinline__ float leaky(float v) { return v > 0.f ? v : 0.01f * v; }

__device__ __forceinline__ float wsumf(float v) {
#pragma unroll
  for (int off = 32; off > 0; off >>= 1) v += __shfl_xor(v, off, 64);
  return v;
}

__device__ __forceinline__ float bcast(float v, int k) {
  return __int_as_float(__builtin_amdgcn_readlane(__float_as_int(v), k));
}

// floats-as-bf16 detector (verified R4-R6)
__device__ __forceinline__ bool detect_bf16(const unsigned short* xs) {
  const int lane = threadIdx.x & 63;
  unsigned a = xs[lane], b = xs[64 + lane];
  unsigned ea = (a >> 7) & 0xFFu, ebx = (b >> 7) & 0xFFu;
  return !__any((int)(ea > 140u || ebx > 140u));
}

// int64-vs-int32 detector (verified R4-R6)
__device__ __forceinline__ bool detect_i64(const int* w) {
  const int lane = threadIdx.x & 63;
  return __all((int)(w[2 * lane + 1] == 0));
}

__device__ __forceinline__ float ldf(const void* p, size_t i, bool bf) {
  return bf ? __bfloat162float(((const __hip_bfloat16*)p)[i]) : ((const float*)p)[i];
}

__device__ __forceinline__ int ldctr(const int* p) {
  return __hip_atomic_load(p, __ATOMIC_RELAXED, __HIP_MEMORY_SCOPE_AGENT);
}

// ---- grid barrier: 2-level arrival (32 groups x 8 blocks) + write-once
// release flag; spinners poll the read-only flag line -> no add/read ping-pong.
// Layout per barrier (1024 uints): [g*16]=group ctr, [512]=global, [528]=release.
__device__ __forceinline__ void gbar(unsigned* bars, int idx, unsigned nb) {
  __syncthreads();
  if (threadIdx.x == 0) {
    unsigned* base = bars + (size_t)idx * 1024;
    __threadfence();
    unsigned g = (unsigned)blockIdx.x >> 3;
    unsigned old = __hip_atomic_fetch_add(base + g * 16, 1u, __ATOMIC_ACQ_REL,
                                          __HIP_MEMORY_SCOPE_AGENT);
    if (old == 7u) {
      unsigned o2 = __hip_atomic_fetch_add(base + 512, 1u, __ATOMIC_ACQ_REL,
                                           __HIP_MEMORY_SCOPE_AGENT);
      if (o2 == (nb >> 3) - 1u)
        __hip_atomic_store(base + 528, 1u, __ATOMIC_RELEASE,
                           __HIP_MEMORY_SCOPE_AGENT);
    }
    while (__hip_atomic_load(base + 528, __ATOMIC_ACQUIRE,
                             __HIP_MEMORY_SCOPE_AGENT) == 0u)
      __builtin_amdgcn_s_sleep(8);
    __threadfence();
  }
  __syncthreads();
}

// ---------------- math (wave-synchronous, no LDS) ---------------------------
__device__ __noinline__ float embed2(const void* x, const float* wts, int v,
                                     int lane, bool bf) {
  float xv = (lane < FIN) ? ldf(x, (size_t)v * FIN + lane, bf) : 0.f;
  float a = wts[OFF_PB + lane];
#pragma unroll
  for (int k = 0; k < FIN; ++k)
    a = fmaf(bcast(xv, k), wts[OFF_PW + k * 64 + lane], a);
  float h = leaky(a);
#pragma unroll
  for (int L = 0; L < 2; ++L) {
    const float* W = wts + OFF_EW + L * 4096;
    float b = wts[OFF_EB + L * 64 + lane];
#pragma unroll
    for (int k = 0; k < 64; ++k) b = fmaf(bcast(h, k), W[k * 64 + lane], b);
    float val = h + leaky(b);
    float mu = wsumf(val) * (1.f / 64.f);
    float d = val - mu;
    float var = wsumf(d * d) * (1.f / 64.f);
    h = d * (1.f / sqrtf(var + EPSLN)) * wts[OFF_G + L * 64 + lane] +
        wts[OFF_BT + L * 64 + lane];
  }
  return h;
}

__device__ __noinline__ float delta2(const float* wts, float mean, int it, int lane) {
  const float* W1 = wts + OFF_W1 + it * 4096;
  float a = wts[OFF_B1 + it * 64 + lane];
#pragma unroll
  for (int k = 0; k < 64; ++k) a = fmaf(bcast(mean, k), W1[k * 64 + lane], a);
  float t1 = leaky(a);
  const float* W2 = wts + OFF_W2 + it * 4096;
  float b = wts[OFF_B2 + it * 64 + lane];
#pragma unroll
  for (int k = 0; k < 64; ++k) b = fmaf(bcast(t1, k), W2[k * 64 + lane], b);
  return b;
}

// ---------------- structures ------------------------------------------------
struct WT {
  const void* src[14];
  int off[14], len[14];
};

struct P {
  float* wts; int* map; unsigned* bars; int* ctr;
  unsigned *bmB, *bmC;
  int *nextSame3, *selfCh3, *chHead3;
  int *node2, *nextSame2, *selfCh2, *chHead2, *chNext2;
  int *node1, *nextSame1, *selfCh1, *chHead1, *chNext1;
  int *node0, *chNext0;
  float *val0, *val1, *val2, *val3, *scores;
};

__device__ void scanE(const int* edge, int E, int nN, bool i64, const unsigned* bm,
                      const int* map, int epoch, const int* nextU, int* headU,
                      int* ctrD, int capD, int* nodeD, int* nextD, int tid, int GT) {
  for (int e = tid; e < E; e += GT) {
    int pv = i64 ? edge[2 * e] : edge[e];
    unsigned pp = (unsigned)pv;
    if (pp >= (unsigned)nN) pp = 0;
    if (bm) {
      if (!((bm[pp >> 5] >> (pp & 31)) & 1u)) continue;
    }
    int m = map[pp];
    if ((m >> 24) != epoch) continue;
    int cv = i64 ? edge[2 * (E + e)] : edge[E + e];
    unsigned cc = (unsigned)cv;
    if (cc >= (unsigned)nN) cc = 0;
    int t = m & 0xFFFFFF;
    while (t >= 0) {  // usually length-1 chain (duplicate frontier nodes)
      int ct = atomicAdd(ctrD, 1);
      if (ct < capD) {
        nodeD[ct] = (int)cc;
        nextD[ct] = atomicExch(&headU[t], ct);
      }
      t = nextU[t];
    }
  }
}

__device__ void regselfF(int cnt, const int* nodeU, int* map, unsigned* bm, int epoch,
                         int* nextU, int* ctrD, int capD, int* nodeD, int* selfU,
                         int tid, int GT) {
  for (int t = tid; t < cnt; t += GT) {
    int n = nodeU[t];
    int enc = (epoch << 24) | t;
    int old = atomicExch(&map[n], enc);
    nextU[t] = ((old >> 24) == epoch) ? (old & 0xFFFFFF) : -1;
    atomicOr(&bm[(unsigned)n >> 5], 1u << (n & 31));
    int s = atomicAdd(ctrD, 1);
    if (s < capD) { nodeD[s] = n; selfU[t] = s; } else selfU[t] = 0;
  }
}

__device__ void evalPhase(int cnt, const int* selfU, const int* headU,
                          const int* nextD, const float* valD, float* valU,
                          const float* wts, int it, int wv, int NW, int lane) {
  for (int t = wv; t < cnt; t += NW) {
    float hv = valD[(size_t)selfU[t] * H + lane];
    float acc = 0.f;
    int k = 0;
    int c = headU[t];
    while (c >= 0) { acc += valD[(size_t)c * H + lane]; ++k; c = nextD[c]; }
    if (k > 0) hv += delta2(wts, acc / (float)k, it, lane);
    valU[(size_t)t * H + lane] = hv;
  }
}

// ---------------- kernels ---------------------------------------------------
__global__ __launch_bounds__(256) void initbars(unsigned* bars, int n) {
  for (int i = blockIdx.x * 256 + threadIdx.x; i < n; i += gridDim.x * 256)
    bars[i] = 0u;
}

__global__ __launch_bounds__(NTHR) void mega(const void* x, const int* edge,
                                             const int* cand, WT T, P p,
                                             int nN, int E, int K, void* out) {
  const int tid = blockIdx.x * NTHR + threadIdx.x;
  const int GT = gridDim.x * NTHR;
  const int lane = threadIdx.x & 63;
  const int wv = blockIdx.x * (NTHR / 64) + (threadIdx.x >> 6);
  const int NW = gridDim.x * (NTHR / 64);
  const unsigned nb = gridDim.x;
  const bool bf = detect_bf16((const unsigned short*)x);
  const bool i64e = detect_i64(edge);
  const bool i64c = detect_i64(cand);
  const int CAP2 = 8 * K, CAP1 = 16 * K, CAP0 = 32 * K;
  const int nWrd = (nN + 31) / 32;

  // ---- A: zero map/bitmaps/heads, prep weights ----
  for (int i = tid; i < nN; i += GT) p.map[i] = 0;
  for (int i = tid; i < nWrd; i += GT) { p.bmB[i] = 0u; p.bmC[i] = 0u; }
  for (int i = tid; i < K; i += GT) p.chHead3[i] = -1;
  for (int i = tid; i < CAP2; i += GT) p.chHead2[i] = -1;
  for (int i = tid; i < CAP1; i += GT) p.chHead1[i] = -1;
  if (tid < 8) p.ctr[tid] = 0;
  for (int i = tid; i < WTS_TOTAL; i += GT) {
    int q = 0;
    while (i >= T.off[q] + T.len[q]) ++q;
    p.wts[i] = ldf(T.src[q], i - T.off[q], bf);
  }
  gbar(p.bars, 0, nb);

  // ---- B: seed L3 = candidates (epoch 1), spawn L2 self-tasks ----
  if (tid < K) {
    int cv = i64c ? cand[2 * tid] : cand[tid];
    unsigned n = (unsigned)cv;
    if (n >= (unsigned)nN) n = 0;
    int old = atomicExch(&p.map[n], (1 << 24) | tid);
    p.nextSame3[tid] = ((old >> 24) == 1) ? (old & 0xFFFFFF) : -1;
    int s = atomicAdd(&p.ctr[0], 1);
    if (s < CAP2) { p.node2[s] = (int)n; p.selfCh3[tid] = s; } else p.selfCh3[tid] = 0;
  }
  gbar(p.bars, 1, nb);

  // ---- C/D/E/F/G: frontier expansion ----
  scanE(edge, E, nN, i64e, nullptr, p.map, 1, p.nextSame3, p.chHead3, &p.ctr[0],
        CAP2, p.node2, p.chNext2, tid, GT);
  gbar(p.bars, 2, nb);

  { int c2 = min(ldctr(&p.ctr[0]), CAP2);
    regselfF(c2, p.node2, p.map, p.bmB, 2, p.nextSame2, &p.ctr[1], CAP1, p.node1,
             p.selfCh2, tid, GT); }
  gbar(p.bars, 3, nb);

  scanE(edge, E, nN, i64e, p.bmB, p.map, 2, p.nextSame2, p.chHead2, &p.ctr[1],
        CAP1, p.node1, p.chNext1, tid, GT);
  gbar(p.bars, 4, nb);

  { int c1 = min(ldctr(&p.ctr[1]), CAP1);
    regselfF(c1, p.node1, p.map, p.bmC, 3, p.nextSame1, &p.ctr[2], CAP0, p.node0,
             p.selfCh1, tid, GT); }
  gbar(p.bars, 5, nb);

  scanE(edge, E, nN, i64e, p.bmC, p.map, 3, p.nextSame1, p.chHead1, &p.ctr[2],
        CAP0, p.node0, p.chNext0, tid, GT);
  gbar(p.bars, 6, nb);

  // ---- H..K: eval levels (one wave per task) ----
  { int c0 = min(ldctr(&p.ctr[2]), CAP0);
    for (int t = wv; t < c0; t += NW)
      p.val0[(size_t)t * H + lane] = embed2(x, p.wts, p.node0[t], lane, bf); }
  gbar(p.bars, 7, nb);

  { int c1 = min(ldctr(&p.ctr[1]), CAP1);
    evalPhase(c1, p.selfCh1, p.chHead1, p.chNext0, p.val0, p.val1, p.wts, 0,
              wv, NW, lane); }
  gbar(p.bars, 8, nb);

  { int c2 = min(ldctr(&p.ctr[0]), CAP2);
    evalPhase(c2, p.selfCh2, p.chHead2, p.chNext1, p.val1, p.val2, p.wts, 1,
              wv, NW, lane); }
  gbar(p.bars, 9, nb);

  // eval L3 fused with score head (task-local)
  for (int t = wv; t < K; t += NW) {
    float hv = p.val2[(size_t)p.selfCh3[t] * H + lane];
    float acc = 0.f;
    int k = 0;
    int c = p.chHead3[t];
    while (c >= 0) { acc += p.val2[(size_t)c * H + lane]; ++k; c = p.chNext2[c]; }
    if (k > 0) hv += delta2(p.wts, acc / (float)k, 2, lane);
    float a = p.wts[OFF_HB1 + lane];
#pragma unroll
    for (int kk = 0; kk < 64; ++kk)
      a = fmaf(bcast(hv, kk), p.wts[OFF_HW1 + kk * 64 + lane], a);
    float sc = wsumf(leaky(a) * p.wts[OFF_HW2 + lane]);
    if (lane == 0) p.scores[t] = sc + p.wts[OFF_HB2];
  }
  gbar(p.bars, 10, nb);

  // ---- softmax + output (block 0 only) ----
  if (blockIdx.x != 0) return;
  __shared__ float red[NTHR];
  const int t = threadIdx.x;
  float mloc = -3.0e38f;
  for (int i = t; i < K; i += NTHR) mloc = fmaxf(mloc, p.scores[i]);
  red[t] = mloc;
  __syncthreads();
  for (int o = NTHR / 2; o > 0; o >>= 1) {
    if (t < o) red[t] = fmaxf(red[t], red[t + o]);
    __syncthreads();
  }
  const float m = red[0];
  __syncthreads();
  float sloc = 0.f;
  for (int i = t; i < K; i += NTHR) sloc += expf(p.scores[i] - m);
  red[t] = sloc;
  __syncthreads();
  for (int o = NTHR / 2; o > 0; o >>= 1) {
    if (t < o) red[t] += red[t + o];
    __syncthreads();
  }
  const float inv = 1.f / red[0];
  for (int i = t; i < K; i += NTHR) {
    float pv = expf(p.scores[i] - m) * inv;
    if (bf) ((__hip_bfloat16*)out)[i] = __float2bfloat16(pv);
    else    ((float*)out)[i] = pv;
  }
}

// ---------------------------------------------------------------------------
extern "C" void kernel_launch(void* const* d_in, const int* in_sizes, int n_in,
                              void* d_out, int out_size, void* d_ws, size_t ws_size,
                              hipStream_t stream) {
  const void* x   = d_in[0];
  const int* edge = (const int*)d_in[1];
  const int* cand = (const int*)d_in[2];
  const int nN = in_sizes[0] / FIN;
  const int E  = in_sizes[1] / 2;
  const int K  = in_sizes[2];

  const int CAP2 = 8 * K, CAP1 = 16 * K, CAP0 = 32 * K;
  const int nWrd = (nN + 31) / 32;
  const int barWords = NBARS * 1024 + 64;  // barriers + ctr block

  auto al = [](size_t b) -> size_t { return (b + 255) & ~(size_t)255; };
  const size_t szW   = (size_t)WTS_TOTAL * sizeof(float);
  const size_t szMap = (size_t)nN * sizeof(int);
  const size_t szBar = (size_t)barWords * sizeof(unsigned);
  const size_t szBm  = (size_t)nWrd * sizeof(unsigned);
  const size_t szK   = (size_t)K * sizeof(int);
  const size_t sz2   = (size_t)CAP2 * sizeof(int);
  const size_t sz1   = (size_t)CAP1 * sizeof(int);
  const size_t sz0   = (size_t)CAP0 * sizeof(int);
  const size_t szV0  = (size_t)CAP0 * H * sizeof(float);
  const size_t szV1  = (size_t)CAP1 * H * sizeof(float);
  const size_t szV2  = (size_t)CAP2 * H * sizeof(float);
  const size_t szV3  = (size_t)K * H * sizeof(float);
  const size_t need = al(szW) + al(szMap) + al(szBar) + 2 * al(szBm) +
                      3 * al(szK) + 5 * al(sz2) + 5 * al(sz1) + 2 * al(sz0) +
                      al(szV0) + al(szV1) + al(szV2) + al(szV3) + al(szK);

  if (K > 2048 || K < 128 || E < 128 || ws_size < need) return;  // zeros diagnostic

  char* wsb = (char*)d_ws;
  size_t off = 0;
  auto carve = [&](size_t bytes) -> void* {
    void* pp = wsb + off;
    off += (bytes + 255) & ~(size_t)255;
    return pp;
  };
  P p;
  p.wts       = (float*)carve(szW);
  p.map       = (int*)carve(szMap);
  p.bars      = (unsigned*)carve(szBar);
  p.ctr       = (int*)(p.bars + NBARS * 1024);
  p.bmB       = (unsigned*)carve(szBm);
  p.bmC       = (unsigned*)carve(szBm);
  p.nextSame3 = (int*)carve(szK);
  p.selfCh3   = (int*)carve(szK);
  p.chHead3   = (int*)carve(szK);
  p.node2     = (int*)carve(sz2);
  p.nextSame2 = (int*)carve(sz2);
  p.selfCh2   = (int*)carve(sz2);
  p.chHead2   = (int*)carve(sz2);
  p.chNext2   = (int*)carve(sz2);
  p.node1     = (int*)carve(sz1);
  p.nextSame1 = (int*)carve(sz1);
  p.selfCh1   = (int*)carve(sz1);
  p.chHead1   = (int*)carve(sz1);
  p.chNext1   = (int*)carve(sz1);
  p.node0     = (int*)carve(sz0);
  p.chNext0   = (int*)carve(sz0);
  p.val0      = (float*)carve(szV0);
  p.val1      = (float*)carve(szV1);
  p.val2      = (float*)carve(szV2);
  p.val3      = (float*)carve(szV3);
  p.scores    = (float*)carve(szK);

  // weight table: plain f32-ified contiguous copies (offsets ascending)
  WT T;
  auto set = [&](int i, const void* s, int o, int l) {
    T.src[i] = s; T.off[i] = o; T.len[i] = l;
  };
  set(0,  d_in[3],  OFF_PW,  1216);
  set(1,  d_in[4],  OFF_PB,  64);
  set(2,  d_in[5],  OFF_EW,  8192);
  set(3,  d_in[6],  OFF_EB,  128);
  set(4,  d_in[7],  OFF_G,   128);
  set(5,  d_in[8],  OFF_BT,  128);
  set(6,  d_in[9],  OFF_W1,  12288);
  set(7,  d_in[11], OFF_W2,  12288);
  set(8,  d_in[10], OFF_B1,  192);
  set(9,  d_in[12], OFF_B2,  192);
  set(10, d_in[13], OFF_HW1, 4096);
  set(11, d_in[14], OFF_HB1, 64);
  set(12, d_in[15], OFF_HW2, 64);
  set(13, d_in[16], OFF_HB2, 1);

  initbars<<<64, 256, 0, stream>>>(p.bars, barWords);
  mega<<<NBLK, NTHR, 0, stream>>>(x, edge, cand, T, p, nN, E, K, d_out);
}

// Round 9
// 443.449 us; speedup vs baseline: 2.1287x; 2.1287x over previous
//
#include <hip/hip_runtime.h>
#include <hip/hip_bf16.h>
#include <math.h>

#define H 64
#define FIN 19
#define EPSLN 1e-5f
#define NBLK 256
#define NTHR 256
#define NBARS 12

// f32 weight workspace layout (element offsets), all natural row-major.
#define OFF_PW   0        // 19*64
#define OFF_PB   1216     // 64
#define OFF_EW   1280     // 2*4096
#define OFF_EB   9472     // 128
#define OFF_G    9600     // 128
#define OFF_BT   9728     // 128
#define OFF_W1   9856     // 3*4096
#define OFF_W2   22144    // 3*4096
#define OFF_B1   34432    // 192
#define OFF_B2   34624    // 192
#define OFF_HW1  34816    // 4096 (natural)
#define OFF_HB1  38912    // 64
#define OFF_HW2  38976    // 64
#define OFF_HB2  39040    // 1
#define WTS_TOTAL 39041

__device__ __forceinline__ float leaky(float v) { return v > 0.f ? v : 0.01f * v; }

__device__ __forceinline__ float wsumf(float v) {
#pragma unroll
  for (int off = 32; off > 0; off >>= 1) v += __shfl_xor(v, off, 64);
  return v;
}

__device__ __forceinline__ float bcast(float v, int k) {
  return __int_as_float(__builtin_amdgcn_readlane(__float_as_int(v), k));
}

// floats-as-bf16 detector (verified R4-R7)
__device__ __forceinline__ bool detect_bf16(const unsigned short* xs) {
  const int lane = threadIdx.x & 63;
  unsigned a = xs[lane], b = xs[64 + lane];
  unsigned ea = (a >> 7) & 0xFFu, ebx = (b >> 7) & 0xFFu;
  return !__any((int)(ea > 140u || ebx > 140u));
}

// int64-vs-int32 detector (verified R4-R7)
__device__ __forceinline__ bool detect_i64(const int* w) {
  const int lane = threadIdx.x & 63;
  return __all((int)(w[2 * lane + 1] == 0));
}

__device__ __forceinline__ float ldf(const void* p, size_t i, bool bf) {
  return bf ? __bfloat162float(((const __hip_bfloat16*)p)[i]) : ((const float*)p)[i];
}

__device__ __forceinline__ int ldctr(const int* p) {
  return __hip_atomic_load(p, __ATOMIC_RELAXED, __HIP_MEMORY_SCOPE_AGENT);
}

// ---- grid barrier, cache-storm-free version ----
// KEY CHANGE vs R6/R7: the spin loop polls with RELAXED atomic loads (atomics
// bypass L2 via sc bits, NO buffer_inv). An agent-scope ACQUIRE load emits
// `buffer_inv sc1` EVERY iteration -> 255 spinning blocks continuously nuke
// every XCD's L2 while stragglers work (the ~77us/barrier in R6/R7).
// Fences hoisted out via __builtin_amdgcn_fence (this ROCm lacks
// __hip_atomic_fence): one RELEASE fence before arrival, one ACQUIRE fence
// after the flag flips. Release flag on its own 128B line (544*4=2176).
__device__ __forceinline__ void gbar(unsigned* bars, int idx, unsigned nb) {
  __syncthreads();
  if (threadIdx.x == 0) {
    unsigned* base = bars + (size_t)idx * 1024;
    __builtin_amdgcn_fence(__ATOMIC_RELEASE, "agent");
    unsigned g = (unsigned)blockIdx.x >> 3;
    unsigned old = __hip_atomic_fetch_add(base + g * 16, 1u, __ATOMIC_RELAXED,
                                          __HIP_MEMORY_SCOPE_AGENT);
    if (old == 7u) {
      unsigned o2 = __hip_atomic_fetch_add(base + 512, 1u, __ATOMIC_RELAXED,
                                           __HIP_MEMORY_SCOPE_AGENT);
      if (o2 == (nb >> 3) - 1u)
        __hip_atomic_store(base + 544, 1u, __ATOMIC_RELAXED,
                           __HIP_MEMORY_SCOPE_AGENT);
    }
    while (__hip_atomic_load(base + 544, __ATOMIC_RELAXED,
                             __HIP_MEMORY_SCOPE_AGENT) == 0u)
      __builtin_amdgcn_s_sleep(8);
    __builtin_amdgcn_fence(__ATOMIC_ACQUIRE, "agent");
  }
  __syncthreads();
}

// ---------------- math (wave-synchronous, no LDS) ---------------------------
__device__ __noinline__ float embed2(const void* x, const float* wts, int v,
                                     int lane, bool bf) {
  float xv = (lane < FIN) ? ldf(x, (size_t)v * FIN + lane, bf) : 0.f;
  float a = wts[OFF_PB + lane];
#pragma unroll
  for (int k = 0; k < FIN; ++k)
    a = fmaf(bcast(xv, k), wts[OFF_PW + k * 64 + lane], a);
  float h = leaky(a);
#pragma unroll
  for (int L = 0; L < 2; ++L) {
    const float* W = wts + OFF_EW + L * 4096;
    float b = wts[OFF_EB + L * 64 + lane];
#pragma unroll
    for (int k = 0; k < 64; ++k) b = fmaf(bcast(h, k), W[k * 64 + lane], b);
    float val = h + leaky(b);
    float mu = wsumf(val) * (1.f / 64.f);
    float d = val - mu;
    float var = wsumf(d * d) * (1.f / 64.f);
    h = d * (1.f / sqrtf(var + EPSLN)) * wts[OFF_G + L * 64 + lane] +
        wts[OFF_BT + L * 64 + lane];
  }
  return h;
}

__device__ __noinline__ float delta2(const float* wts, float mean, int it, int lane) {
  const float* W1 = wts + OFF_W1 + it * 4096;
  float a = wts[OFF_B1 + it * 64 + lane];
#pragma unroll
  for (int k = 0; k < 64; ++k) a = fmaf(bcast(mean, k), W1[k * 64 + lane], a);
  float t1 = leaky(a);
  const float* W2 = wts + OFF_W2 + it * 4096;
  float b = wts[OFF_B2 + it * 64 + lane];
#pragma unroll
  for (int k = 0; k < 64; ++k) b = fmaf(bcast(t1, k), W2[k * 64 + lane], b);
  return b;
}

// ---------------- structures ------------------------------------------------
struct WT {
  const void* src[14];
  int off[14], len[14];
};

struct P {
  float* wts; int* map; unsigned* bars; int* ctr;
  unsigned *bmB, *bmC;
  int *nextSame3, *selfCh3, *chHead3;
  int *node2, *nextSame2, *selfCh2, *chHead2, *chNext2;
  int *node1, *nextSame1, *selfCh1, *chHead1, *chNext1;
  int *node0, *chNext0;
  float *val0, *val1, *val2, *val3, *scores;
};

__device__ void scanE(const int* edge, int E, int nN, bool i64, const unsigned* bm,
                      const int* map, int epoch, const int* nextU, int* headU,
                      int* ctrD, int capD, int* nodeD, int* nextD, int tid, int GT) {
  for (int e = tid; e < E; e += GT) {
    int pv = i64 ? edge[2 * e] : edge[e];
    unsigned pp = (unsigned)pv;
    if (pp >= (unsigned)nN) pp = 0;
    if (bm) {
      if (!((bm[pp >> 5] >> (pp & 31)) & 1u)) continue;
    }
    int m = map[pp];
    if ((m >> 24) != epoch) continue;
    int cv = i64 ? edge[2 * (E + e)] : edge[E + e];
    unsigned cc = (unsigned)cv;
    if (cc >= (unsigned)nN) cc = 0;
    int t = m & 0xFFFFFF;
    while (t >= 0) {  // usually length-1 chain (duplicate frontier nodes)
      int ct = atomicAdd(ctrD, 1);
      if (ct < capD) {
        nodeD[ct] = (int)cc;
        nextD[ct] = atomicExch(&headU[t], ct);
      }
      t = nextU[t];
    }
  }
}

__device__ void regselfF(int cnt, const int* nodeU, int* map, unsigned* bm, int epoch,
                         int* nextU, int* ctrD, int capD, int* nodeD, int* selfU,
                         int tid, int GT) {
  for (int t = tid; t < cnt; t += GT) {
    int n = nodeU[t];
    int enc = (epoch << 24) | t;
    int old = atomicExch(&map[n], enc);
    nextU[t] = ((old >> 24) == epoch) ? (old & 0xFFFFFF) : -1;
    atomicOr(&bm[(unsigned)n >> 5], 1u << (n & 31));
    int s = atomicAdd(ctrD, 1);
    if (s < capD) { nodeD[s] = n; selfU[t] = s; } else selfU[t] = 0;
  }
}

__device__ void evalPhase(int cnt, const int* selfU, const int* headU,
                          const int* nextD, const float* valD, float* valU,
                          const float* wts, int it, int wv, int NW, int lane) {
  for (int t = wv; t < cnt; t += NW) {
    float hv = valD[(size_t)selfU[t] * H + lane];
    float acc = 0.f;
    int k = 0;
    int c = headU[t];
    while (c >= 0) { acc += valD[(size_t)c * H + lane]; ++k; c = nextD[c]; }
    if (k > 0) hv += delta2(wts, acc / (float)k, it, lane);
    valU[(size_t)t * H + lane] = hv;
  }
}

// ---------------- kernels ---------------------------------------------------
__global__ __launch_bounds__(256) void initbars(unsigned* bars, int n) {
  for (int i = blockIdx.x * 256 + threadIdx.x; i < n; i += gridDim.x * 256)
    bars[i] = 0u;
}

__global__ __launch_bounds__(NTHR) void mega(const void* x, const int* edge,
                                             const int* cand, WT T, P p,
                                             int nN, int E, int K, void* out) {
  const int tid = blockIdx.x * NTHR + threadIdx.x;
  const int GT = gridDim.x * NTHR;
  const int lane = threadIdx.x & 63;
  const int wv = blockIdx.x * (NTHR / 64) + (threadIdx.x >> 6);
  const int NW = gridDim.x * (NTHR / 64);
  const unsigned nb = gridDim.x;
  const bool bf = detect_bf16((const unsigned short*)x);
  const bool i64e = detect_i64(edge);
  const bool i64c = detect_i64(cand);
  const int CAP2 = 8 * K, CAP1 = 16 * K, CAP0 = 32 * K;
  const int nWrd = (nN + 31) / 32;

  // ---- A: zero map/bitmaps/heads, prep weights ----
  for (int i = tid; i < nN; i += GT) p.map[i] = 0;
  for (int i = tid; i < nWrd; i += GT) { p.bmB[i] = 0u; p.bmC[i] = 0u; }
  for (int i = tid; i < K; i += GT) p.chHead3[i] = -1;
  for (int i = tid; i < CAP2; i += GT) p.chHead2[i] = -1;
  for (int i = tid; i < CAP1; i += GT) p.chHead1[i] = -1;
  if (tid < 8) p.ctr[tid] = 0;
  for (int i = tid; i < WTS_TOTAL; i += GT) {
    int q = 0;
    while (i >= T.off[q] + T.len[q]) ++q;
    p.wts[i] = ldf(T.src[q], i - T.off[q], bf);
  }
  gbar(p.bars, 0, nb);

  // ---- B: seed L3 = candidates (epoch 1), spawn L2 self-tasks ----
  if (tid < K) {
    int cv = i64c ? cand[2 * tid] : cand[tid];
    unsigned n = (unsigned)cv;
    if (n >= (unsigned)nN) n = 0;
    int old = atomicExch(&p.map[n], (1 << 24) | tid);
    p.nextSame3[tid] = ((old >> 24) == 1) ? (old & 0xFFFFFF) : -1;
    int s = atomicAdd(&p.ctr[0], 1);
    if (s < CAP2) { p.node2[s] = (int)n; p.selfCh3[tid] = s; } else p.selfCh3[tid] = 0;
  }
  gbar(p.bars, 1, nb);

  // ---- C/D/E/F/G: frontier expansion ----
  scanE(edge, E, nN, i64e, nullptr, p.map, 1, p.nextSame3, p.chHead3, &p.ctr[0],
        CAP2, p.node2, p.chNext2, tid, GT);
  gbar(p.bars, 2, nb);

  { int c2 = min(ldctr(&p.ctr[0]), CAP2);
    regselfF(c2, p.node2, p.map, p.bmB, 2, p.nextSame2, &p.ctr[1], CAP1, p.node1,
             p.selfCh2, tid, GT); }
  gbar(p.bars, 3, nb);

  scanE(edge, E, nN, i64e, p.bmB, p.map, 2, p.nextSame2, p.chHead2, &p.ctr[1],
        CAP1, p.node1, p.chNext1, tid, GT);
  gbar(p.bars, 4, nb);

  { int c1 = min(ldctr(&p.ctr[1]), CAP1);
    regselfF(c1, p.node1, p.map, p.bmC, 3, p.nextSame1, &p.ctr[2], CAP0, p.node0,
             p.selfCh1, tid, GT); }
  gbar(p.bars, 5, nb);

  scanE(edge, E, nN, i64e, p.bmC, p.map, 3, p.nextSame1, p.chHead1, &p.ctr[2],
        CAP0, p.node0, p.chNext0, tid, GT);
  gbar(p.bars, 6, nb);

  // ---- H..K: eval levels (one wave per task) ----
  { int c0 = min(ldctr(&p.ctr[2]), CAP0);
    for (int t = wv; t < c0; t += NW)
      p.val0[(size_t)t * H + lane] = embed2(x, p.wts, p.node0[t], lane, bf); }
  gbar(p.bars, 7, nb);

  { int c1 = min(ldctr(&p.ctr[1]), CAP1);
    evalPhase(c1, p.selfCh1, p.chHead1, p.chNext0, p.val0, p.val1, p.wts, 0,
              wv, NW, lane); }
  gbar(p.bars, 8, nb);

  { int c2 = min(ldctr(&p.ctr[0]), CAP2);
    evalPhase(c2, p.selfCh2, p.chHead2, p.chNext1, p.val1, p.val2, p.wts, 1,
              wv, NW, lane); }
  gbar(p.bars, 9, nb);

  // eval L3 fused with score head (task-local)
  for (int t = wv; t < K; t += NW) {
    float hv = p.val2[(size_t)p.selfCh3[t] * H + lane];
    float acc = 0.f;
    int k = 0;
    int c = p.chHead3[t];
    while (c >= 0) { acc += p.val2[(size_t)c * H + lane]; ++k; c = p.chNext2[c]; }
    if (k > 0) hv += delta2(p.wts, acc / (float)k, 2, lane);
    float a = p.wts[OFF_HB1 + lane];
#pragma unroll
    for (int kk = 0; kk < 64; ++kk)
      a = fmaf(bcast(hv, kk), p.wts[OFF_HW1 + kk * 64 + lane], a);
    float sc = wsumf(leaky(a) * p.wts[OFF_HW2 + lane]);
    if (lane == 0) p.scores[t] = sc + p.wts[OFF_HB2];
  }
  gbar(p.bars, 10, nb);

  // ---- softmax + output (block 0 only) ----
  if (blockIdx.x != 0) return;
  __shared__ float red[NTHR];
  const int t = threadIdx.x;
  float mloc = -3.0e38f;
  for (int i = t; i < K; i += NTHR) mloc = fmaxf(mloc, p.scores[i]);
  red[t] = mloc;
  __syncthreads();
  for (int o = NTHR / 2; o > 0; o >>= 1) {
    if (t < o) red[t] = fmaxf(red[t], red[t + o]);
    __syncthreads();
  }
  const float m = red[0];
  __syncthreads();
  float sloc = 0.f;
  for (int i = t; i < K; i += NTHR) sloc += expf(p.scores[i] - m);
  red[t] = sloc;
  __syncthreads();
  for (int o = NTHR / 2; o > 0; o >>= 1) {
    if (t < o) red[t] += red[t + o];
    __syncthreads();
  }
  const float inv = 1.f / red[0];
  for (int i = t; i < K; i += NTHR) {
    float pv = expf(p.scores[i] - m) * inv;
    if (bf) ((__hip_bfloat16*)out)[i] = __float2bfloat16(pv);
    else    ((float*)out)[i] = pv;
  }
}

// ---------------------------------------------------------------------------
extern "C" void kernel_launch(void* const* d_in, const int* in_sizes, int n_in,
                              void* d_out, int out_size, void* d_ws, size_t ws_size,
                              hipStream_t stream) {
  const void* x   = d_in[0];
  const int* edge = (const int*)d_in[1];
  const int* cand = (const int*)d_in[2];
  const int nN = in_sizes[0] / FIN;
  const int E  = in_sizes[1] / 2;
  const int K  = in_sizes[2];

  const int CAP2 = 8 * K, CAP1 = 16 * K, CAP0 = 32 * K;
  const int nWrd = (nN + 31) / 32;
  const int barWords = NBARS * 1024 + 64;  // barriers + ctr block

  auto al = [](size_t b) -> size_t { return (b + 255) & ~(size_t)255; };
  const size_t szW   = (size_t)WTS_TOTAL * sizeof(float);
  const size_t szMap = (size_t)nN * sizeof(int);
  const size_t szBar = (size_t)barWords * sizeof(unsigned);
  const size_t szBm  = (size_t)nWrd * sizeof(unsigned);
  const size_t szK   = (size_t)K * sizeof(int);
  const size_t sz2   = (size_t)CAP2 * sizeof(int);
  const size_t sz1   = (size_t)CAP1 * sizeof(int);
  const size_t sz0   = (size_t)CAP0 * sizeof(int);
  const size_t szV0  = (size_t)CAP0 * H * sizeof(float);
  const size_t szV1  = (size_t)CAP1 * H * sizeof(float);
  const size_t szV2  = (size_t)CAP2 * H * sizeof(float);
  const size_t szV3  = (size_t)K * H * sizeof(float);
  const size_t need = al(szW) + al(szMap) + al(szBar) + 2 * al(szBm) +
                      3 * al(szK) + 5 * al(sz2) + 5 * al(sz1) + 2 * al(sz0) +
                      al(szV0) + al(szV1) + al(szV2) + al(szV3) + al(szK);

  if (K > 2048 || K < 128 || E < 128 || ws_size < need) return;  // zeros diagnostic

  char* wsb = (char*)d_ws;
  size_t off = 0;
  auto carve = [&](size_t bytes) -> void* {
    void* pp = wsb + off;
    off += (bytes + 255) & ~(size_t)255;
    return pp;
  };
  P p;
  p.wts       = (float*)carve(szW);
  p.map       = (int*)carve(szMap);
  p.bars      = (unsigned*)carve(szBar);
  p.ctr       = (int*)(p.bars + NBARS * 1024);
  p.bmB       = (unsigned*)carve(szBm);
  p.bmC       = (unsigned*)carve(szBm);
  p.nextSame3 = (int*)carve(szK);
  p.selfCh3   = (int*)carve(szK);
  p.chHead3   = (int*)carve(szK);
  p.node2     = (int*)carve(sz2);
  p.nextSame2 = (int*)carve(sz2);
  p.selfCh2   = (int*)carve(sz2);
  p.chHead2   = (int*)carve(sz2);
  p.chNext2   = (int*)carve(sz2);
  p.node1     = (int*)carve(sz1);
  p.nextSame1 = (int*)carve(sz1);
  p.selfCh1   = (int*)carve(sz1);
  p.chHead1   = (int*)carve(sz1);
  p.chNext1   = (int*)carve(sz1);
  p.node0     = (int*)carve(sz0);
  p.chNext0   = (int*)carve(sz0);
  p.val0      = (float*)carve(szV0);
  p.val1      = (float*)carve(szV1);
  p.val2      = (float*)carve(szV2);
  p.val3      = (float*)carve(szV3);
  p.scores    = (float*)carve(szK);

  // weight table: plain f32-ified contiguous copies (offsets ascending)
  WT T;
  auto set = [&](int i, const void* s, int o, int l) {
    T.src[i] = s; T.off[i] = o; T.len[i] = l;
  };
  set(0,  d_in[3],  OFF_PW,  1216);
  set(1,  d_in[4],  OFF_PB,  64);
  set(2,  d_in[5],  OFF_EW,  8192);
  set(3,  d_in[6],  OFF_EB,  128);
  set(4,  d_in[7],  OFF_G,   128);
  set(5,  d_in[8],  OFF_BT,  128);
  set(6,  d_in[9],  OFF_W1,  12288);
  set(7,  d_in[11], OFF_W2,  12288);
  set(8,  d_in[10], OFF_B1,  192);
  set(9,  d_in[12], OFF_B2,  192);
  set(10, d_in[13], OFF_HW1, 4096);
  set(11, d_in[14], OFF_HB1, 64);
  set(12, d_in[15], OFF_HW2, 64);
  set(13, d_in[16], OFF_HB2, 1);

  initbars<<<64, 256, 0, stream>>>(p.bars, barWords);
  mega<<<NBLK, NTHR, 0, stream>>>(x, edge, cand, T, p, nN, E, K, d_out);
}